// Round 4
// baseline (2270.932 us; speedup 1.0000x reference)
//
#include <hip/hip_runtime.h>
#include <cstdint>

// B=4, S=2048, d=2048, dff=8192. ALL inputs fp32 (per reference), output fp32.
// Internally bf16 MFMA with fp32 accumulate; fp32->bf16 conversion at staging.
//
// ws (bytes): x1[0,32M) bf16 | Q[32,64) bf16 | K[64,96) bf16 | sc[96,112) fp32
//             src2 fp32 [32,96) after attention | h2 bf16 [0,32) after proj.  Peak 112 MiB.
// d_out (64 MiB fp32) as scratch: Vt bf16 [0,32M) | attn bf16 [32,64M) | f1 bf16 [0,32M).

typedef __attribute__((ext_vector_type(8))) short short8;
typedef __attribute__((ext_vector_type(4))) float floatx4;

#define PLANE 16777216L   // 8192*2048 elements (Q->K plane stride in ws)
#define SS    4194304L    // 2048*2048 elements (per-batch matrix)

__device__ __forceinline__ float bf2f(unsigned short u) {
    union { unsigned int i; float f; } v; v.i = ((unsigned int)u) << 16; return v.f;
}
__device__ __forceinline__ unsigned short f2bf(float f) {
    union { float f; unsigned int i; } v; v.f = f;
    unsigned int x = v.i;
    return (unsigned short)((x + 0x7FFFu + ((x >> 16) & 1u)) >> 16);
}
__device__ __forceinline__ uint4 pack8(float4 a, float4 b) {
    unsigned short o[8];
    o[0] = f2bf(a.x); o[1] = f2bf(a.y); o[2] = f2bf(a.z); o[3] = f2bf(a.w);
    o[4] = f2bf(b.x); o[5] = f2bf(b.y); o[6] = f2bf(b.z); o[7] = f2bf(b.w);
    return *(uint4*)o;
}

#define EM_QKV  0
#define EM_SC   1
#define EM_PV   2
#define EM_PROJ 3
#define EM_FFN1 4
#define EM_F2A  5

// C(M,N) = A(M,K) @ Bt(N,K)^T. A: lda==K. 128x128 tile, BK=32, 256 thr = 4 waves,
// each wave 64x64 via 4x4 mfma_f32_16x16x32_bf16 (C/D map verified m89/m91).
template<bool AF32, bool BF32, int EM>
__launch_bounds__(256, 2)
__global__ void gemm_bt(const void* __restrict__ Av,
                        const void* __restrict__ Bv,
                        void* __restrict__ Cv,
                        int N, int K, int ldb,
                        const float* __restrict__ bias,
                        const unsigned short* __restrict__ resid16,
                        unsigned short* __restrict__ outQ,
                        unsigned short* __restrict__ outVt)
{
    constexpr int BM = 128, BN = 128, BK = 32, LDST = 40;
    __shared__ __align__(16) unsigned short As[BM * LDST];
    __shared__ __align__(16) unsigned short Bs[BN * LDST];

    const int m0 = blockIdx.x * BM, n0 = blockIdx.y * BN;
    if (EM == EM_SC && n0 > m0 + (BM - 1)) return;   // fully-masked causal tile

    int kmax = K;
    if (EM == EM_PV) { kmax = m0 + BM; if (kmax > K) kmax = K; }  // P zero past causal edge
    const int nsteps = kmax / BK;

    const int t = threadIdx.x;
    const int lane = t & 63, wave = t >> 6;
    const int q = lane >> 4, ln = lane & 15;
    const int wm = (wave >> 1) * 64, wn = (wave & 1) * 64;
    const int r0 = t >> 2, c0 = t & 3;

    // ---- A staging ----
    const unsigned short* Ag0_16; const unsigned short* Ag1_16;
    const float* Ag0_32; const float* Ag1_32;
    uint4 ra0, ra1;
    float4 fa00, fa01, fa10, fa11;
    if constexpr (AF32) {
        const float* A32 = (const float*)Av;
        Ag0_32 = A32 + (long)(m0 + r0) * K + c0 * 8;
        Ag1_32 = Ag0_32 + (long)64 * K;
        fa00 = *(const float4*)Ag0_32; fa01 = *(const float4*)(Ag0_32 + 4);
        fa10 = *(const float4*)Ag1_32; fa11 = *(const float4*)(Ag1_32 + 4);
    } else {
        const unsigned short* A16 = (const unsigned short*)Av;
        Ag0_16 = A16 + (long)(m0 + r0) * K + c0 * 8;
        Ag1_16 = Ag0_16 + (long)64 * K;
        ra0 = *(const uint4*)Ag0_16;
        ra1 = *(const uint4*)Ag1_16;
    }
    // ---- B staging ----
    const unsigned short* Bg0_16; const unsigned short* Bg1_16;
    const float* Bg0_32; const float* Bg1_32;
    uint4 rb0, rb1;
    float4 fb00, fb01, fb10, fb11;
    if constexpr (BF32) {
        const float* B32 = (const float*)Bv;
        Bg0_32 = B32 + (long)(n0 + r0) * ldb + c0 * 8;
        Bg1_32 = Bg0_32 + (long)64 * ldb;
        fb00 = *(const float4*)Bg0_32; fb01 = *(const float4*)(Bg0_32 + 4);
        fb10 = *(const float4*)Bg1_32; fb11 = *(const float4*)(Bg1_32 + 4);
    } else {
        const unsigned short* B16 = (const unsigned short*)Bv;
        Bg0_16 = B16 + (long)(n0 + r0) * ldb + c0 * 8;
        Bg1_16 = Bg0_16 + (long)64 * ldb;
        rb0 = *(const uint4*)Bg0_16;
        rb1 = *(const uint4*)Bg1_16;
    }

    floatx4 acc[4][4];
#pragma unroll
    for (int i = 0; i < 4; ++i)
#pragma unroll
        for (int j = 0; j < 4; ++j) acc[i][j] = (floatx4){0.f, 0.f, 0.f, 0.f};

    const int sA0 = r0 * LDST + c0 * 8;
    const int sA1 = (r0 + 64) * LDST + c0 * 8;

    for (int s = 0; s < nsteps; ++s) {
        __syncthreads();
        if constexpr (AF32) {
            *(uint4*)&As[sA0] = pack8(fa00, fa01);
            *(uint4*)&As[sA1] = pack8(fa10, fa11);
        } else {
            *(uint4*)&As[sA0] = ra0;
            *(uint4*)&As[sA1] = ra1;
        }
        if constexpr (BF32) {
            *(uint4*)&Bs[sA0] = pack8(fb00, fb01);
            *(uint4*)&Bs[sA1] = pack8(fb10, fb11);
        } else {
            *(uint4*)&Bs[sA0] = rb0;
            *(uint4*)&Bs[sA1] = rb1;
        }
        __syncthreads();
        if (s + 1 < nsteps) {
            const long off = (long)(s + 1) * BK;
            if constexpr (AF32) {
                fa00 = *(const float4*)(Ag0_32 + off); fa01 = *(const float4*)(Ag0_32 + off + 4);
                fa10 = *(const float4*)(Ag1_32 + off); fa11 = *(const float4*)(Ag1_32 + off + 4);
            } else {
                ra0 = *(const uint4*)(Ag0_16 + off);
                ra1 = *(const uint4*)(Ag1_16 + off);
            }
            if constexpr (BF32) {
                fb00 = *(const float4*)(Bg0_32 + off); fb01 = *(const float4*)(Bg0_32 + off + 4);
                fb10 = *(const float4*)(Bg1_32 + off); fb11 = *(const float4*)(Bg1_32 + off + 4);
            } else {
                rb0 = *(const uint4*)(Bg0_16 + off);
                rb1 = *(const uint4*)(Bg1_16 + off);
            }
        }
        short8 af[4], bfr[4];
#pragma unroll
        for (int i = 0; i < 4; ++i) af[i]  = *(const short8*)&As[(wm + 16 * i + ln) * LDST + q * 8];
#pragma unroll
        for (int j = 0; j < 4; ++j) bfr[j] = *(const short8*)&Bs[(wn + 16 * j + ln) * LDST + q * 8];
#pragma unroll
        for (int i = 0; i < 4; ++i)
#pragma unroll
            for (int j = 0; j < 4; ++j)
                acc[i][j] = __builtin_amdgcn_mfma_f32_16x16x32_bf16(af[i], bfr[j], acc[i][j], 0, 0, 0);
    }

    // epilogue: within 16x16 tile, row = q*4+reg, col = ln
#pragma unroll
    for (int i = 0; i < 4; ++i) {
#pragma unroll
        for (int r = 0; r < 4; ++r) {
            const int row = m0 + wm + 16 * i + q * 4 + r;
#pragma unroll
            for (int j = 0; j < 4; ++j) {
                const int col = n0 + wn + 16 * j + ln;
                float v = acc[i][j][r];
                const long idx = (long)row * N + col;
                if constexpr (EM == EM_QKV) {
                    v += bias[col];
                    const unsigned short vb = f2bf(v);
                    const int p = col >> 11, c2 = col & 2047;
                    if (p == 0)      outQ[(long)row * 2048 + c2] = vb;
                    else if (p == 1) (outQ + PLANE)[(long)row * 2048 + c2] = vb;
                    else             outVt[(long)(row >> 11) * SS + (long)c2 * 2048 + (row & 2047)] = vb;
                } else if constexpr (EM == EM_SC) {
                    ((float*)Cv)[idx] = v;
                } else if constexpr (EM == EM_PV) {
                    ((unsigned short*)Cv)[idx] = f2bf(v);
                } else if constexpr (EM == EM_PROJ) {
                    v += bias[col] + bf2f(resid16[idx]);    // resid = LN1 out (bf16 x1)
                    ((float*)Cv)[idx] = v;
                } else if constexpr (EM == EM_FFN1) {
                    v = fmaxf(v + bias[col], 0.f);
                    ((unsigned short*)Cv)[idx] = f2bf(v);
                } else { // EM_F2A: accumulate into fp32 src2 (residual already there)
                    ((float*)Cv)[idx] += v;
                }
            }
        }
    }
}

// LayerNorm: fp32 in (2048 cols), bf16 out; fp32 gamma/beta.
__launch_bounds__(256)
__global__ void layernorm_k(const float* __restrict__ X, unsigned short* __restrict__ Y,
                            const float* __restrict__ g, const float* __restrict__ be)
{
    const int row = blockIdx.x, t = threadIdx.x;
    const float* Xr = X + (long)row * 2048 + t * 8;
    float4 v0 = *(const float4*)Xr;
    float4 v1 = *(const float4*)(Xr + 4);
    float x[8] = {v0.x, v0.y, v0.z, v0.w, v1.x, v1.y, v1.z, v1.w};
    float s = 0.f, ss = 0.f;
#pragma unroll
    for (int k = 0; k < 8; ++k) { s += x[k]; ss += x[k] * x[k]; }
    for (int off = 32; off; off >>= 1) { s += __shfl_down(s, off, 64); ss += __shfl_down(ss, off, 64); }
    __shared__ float red[8];
    const int wave = t >> 6, lane = t & 63;
    if (lane == 0) { red[wave] = s; red[4 + wave] = ss; }
    __syncthreads();
    s  = red[0] + red[1] + red[2] + red[3];
    ss = red[4] + red[5] + red[6] + red[7];
    const float mean = s * (1.f / 2048.f);
    const float var  = ss * (1.f / 2048.f) - mean * mean;
    const float rstd = rsqrtf(var + 1e-5f);
    unsigned short o[8];
#pragma unroll
    for (int k = 0; k < 8; ++k) {
        const int col = t * 8 + k;
        o[k] = f2bf((x[k] - mean) * rstd * g[col] + be[col]);
    }
    *(uint4*)(Y + (long)row * 2048 + t * 8) = *(uint4*)o;
}

// In-place RoPE on bf16 Q (blockIdx.y=0) / K (=1), replicating the reference quirk:
// emb = concat(sin(sp),cos(sp)); c=cos(emb), s=sin(emb); rh = concat(-x[::2], x[1::2]).
__launch_bounds__(256)
__global__ void rope_inplace(unsigned short* __restrict__ Q, unsigned short* __restrict__ K)
{
    __shared__ __align__(16) unsigned short rowbuf[2048];
    const int row = blockIdx.x;              // 0..8191 (b*2048+p)
    const int mtx = blockIdx.y;
    unsigned short* X = (mtx ? K : Q) + (long)row * 2048;
    const int t = threadIdx.x;
    *(uint4*)&rowbuf[t * 8] = *(const uint4*)(X + t * 8);
    __syncthreads();
    const int p = row & 2047;
    const float sgn = mtx ? -1.f : 1.f;
    unsigned short o[8];
#pragma unroll
    for (int e = 0; e < 8; ++e) {
        const int j = t * 8 + e;
        const int i = j & 1023;
        const float freq = __expf(-(float)i * (9.210340371976184f / 1024.0f)); // 10000^(-i/1024)
        const float sp = (float)p * freq;
        const float emb = (j < 1024) ? sinf(sp) : cosf(sp);
        float se, ce;
        sincosf(emb, &se, &ce);
        const int pj = (j < 1024) ? (2 * j) : (2 * j - 2047);
        float xp = bf2f(rowbuf[pj]);
        if (j < 1024) xp = -xp;
        o[e] = f2bf(bf2f(rowbuf[j]) * ce + sgn * xp * se);
    }
    *(uint4*)(X + t * 8) = *(uint4*)o;
}

// Causal softmax in-place on one batch's fp32 scores (2048 x 2048); writes full rows
// (zeros past the causal edge) so PV can read any k < kmax.
__launch_bounds__(256)
__global__ void softmax_causal(float* __restrict__ S)
{
    const int qq = blockIdx.x;
    const int L = qq + 1;
    float* srow = S + (long)qq * 2048;
    const int t = threadIdx.x;
    const float scale = 0.022097086912079608f; // 1/sqrt(2048)
    float vals[8];
    float m = -1e30f;
#pragma unroll
    for (int u = 0; u < 8; ++u) {
        const int i2 = t + 256 * u;
        vals[u] = (i2 < L) ? srow[i2] * scale : -1e30f;
        m = fmaxf(m, vals[u]);
    }
    for (int off = 32; off; off >>= 1) m = fmaxf(m, __shfl_down(m, off, 64));
    __shared__ float red[8];
    const int wave = t >> 6, lane = t & 63;
    if (lane == 0) red[wave] = m;
    __syncthreads();
    m = fmaxf(fmaxf(red[0], red[1]), fmaxf(red[2], red[3]));
    float sum = 0.f;
#pragma unroll
    for (int u = 0; u < 8; ++u) {
        float e = __expf(vals[u] - m);
        e = (t + 256 * u < L) ? e : 0.f;
        vals[u] = e; sum += e;
    }
    for (int off = 32; off; off >>= 1) sum += __shfl_down(sum, off, 64);
    if (lane == 0) red[4 + wave] = sum;
    __syncthreads();
    sum = red[4] + red[5] + red[6] + red[7];
    const float inv = 1.0f / sum;
#pragma unroll
    for (int u = 0; u < 8; ++u) srow[t + 256 * u] = vals[u] * inv;
}

// out = src2 + b2 (fp32 out; src2 already holds residual + FFN2 accumulation)
__launch_bounds__(256)
__global__ void final_add(const float* __restrict__ src2, const float* __restrict__ b2,
                          float* __restrict__ out)
{
    const int row = blockIdx.x, t = threadIdx.x;
    const long base = (long)row * 2048 + t * 8;
    float4 a0 = *(const float4*)(src2 + base);
    float4 a1 = *(const float4*)(src2 + base + 4);
    float4 c0 = *(const float4*)(b2 + t * 8);
    float4 c1 = *(const float4*)(b2 + t * 8 + 4);
    a0.x += c0.x; a0.y += c0.y; a0.z += c0.z; a0.w += c0.w;
    a1.x += c1.x; a1.y += c1.y; a1.z += c1.z; a1.w += c1.w;
    *(float4*)(out + base) = a0;
    *(float4*)(out + base + 4) = a1;
}

extern "C" void kernel_launch(void* const* d_in, const int* in_sizes, int n_in,
                              void* d_out, int out_size, void* d_ws, size_t ws_size,
                              hipStream_t stream)
{
    const float* src  = (const float*)d_in[0];
    const float* Wqkv = (const float*)d_in[1];
    const float* bqkv = (const float*)d_in[2];
    const float* Wo   = (const float*)d_in[3];
    const float* bo   = (const float*)d_in[4];
    const float* W1   = (const float*)d_in[5];
    const float* b1   = (const float*)d_in[6];
    const float* W2   = (const float*)d_in[7];
    const float* b2   = (const float*)d_in[8];
    const float* g1   = (const float*)d_in[9];
    const float* be1  = (const float*)d_in[10];
    const float* g2   = (const float*)d_in[11];
    const float* be2  = (const float*)d_in[12];

    char* ws = (char*)d_ws;
    const long MB = 1LL << 20;
    unsigned short* x1   = (unsigned short*)ws;                 // [0,32M) bf16 LN1 out
    unsigned short* Q    = (unsigned short*)(ws + 32 * MB);     // [32,64) bf16
    unsigned short* Kb   = (unsigned short*)(ws + 64 * MB);     // [64,96) bf16 (contiguous after Q: PLANE)
    float*          sc   = (float*)(ws + 96 * MB);              // [96,112) fp32 per-batch scores
    float*          src2 = (float*)(ws + 32 * MB);              // [32,96) fp32 after attention
    unsigned short* h2   = (unsigned short*)ws;                 // [0,32) bf16 after proj

    char* ob = (char*)d_out;
    unsigned short* Vt   = (unsigned short*)ob;                 // [0,32M) bf16
    unsigned short* attn = (unsigned short*)(ob + 32 * MB);     // [32,64M) bf16
    unsigned short* f1   = (unsigned short*)ob;                 // [0,32M) bf16 after proj
    float*          out  = (float*)d_out;

    const dim3 blk(256);

    layernorm_k<<<8192, blk, 0, stream>>>(src, x1, g1, be1);
    // QKV: A = x1 bf16, B = Wqkv fp32 (6144x2048). Epilogue routes Q/K planes + transposed V.
    gemm_bt<false, true, EM_QKV><<<dim3(64, 48), blk, 0, stream>>>(
        x1, Wqkv, nullptr, 6144, 2048, 2048, bqkv, nullptr, Q, Vt);
    rope_inplace<<<dim3(8192, 2), blk, 0, stream>>>(Q, Kb);

    for (int b = 0; b < 4; ++b) {
        gemm_bt<false, false, EM_SC><<<dim3(16, 16), blk, 0, stream>>>(
            Q + b * SS, Kb + b * SS, sc, 2048, 2048, 2048, nullptr, nullptr, nullptr, nullptr);
        softmax_causal<<<2048, blk, 0, stream>>>(sc);
        gemm_bt<true, false, EM_PV><<<dim3(16, 16), blk, 0, stream>>>(
            sc, Vt + b * SS, attn + b * SS, 2048, 2048, 2048, nullptr, nullptr, nullptr, nullptr);
    }

    // proj: A = attn bf16 (8192x2048 contiguous), B = Wo fp32; src2 = attn@Wo^T + bo + x1
    gemm_bt<false, true, EM_PROJ><<<dim3(64, 16), blk, 0, stream>>>(
        attn, Wo, src2, 2048, 2048, 2048, bo, x1, nullptr, nullptr);
    layernorm_k<<<8192, blk, 0, stream>>>(src2, h2, g2, be2);

    // FFN in 4 f-chunks of 2048; FFN2 accumulates into src2 (residual already there).
    for (int c = 0; c < 4; ++c) {
        gemm_bt<false, true, EM_FFN1><<<dim3(64, 16), blk, 0, stream>>>(
            h2, W1 + (long)c * 2048 * 2048, f1, 2048, 2048, 2048,
            b1 + c * 2048, nullptr, nullptr, nullptr);
        gemm_bt<false, true, EM_F2A><<<dim3(64, 16), blk, 0, stream>>>(
            f1, W2 + c * 2048, src2, 2048, 2048, 8192, nullptr, nullptr, nullptr, nullptr);
    }
    final_add<<<8192, blk, 0, stream>>>(src2, b2, out);
}

// Round 5
// 1714.528 us; speedup vs baseline: 1.3245x; 1.3245x over previous
//
#include <hip/hip_runtime.h>
#include <cstdint>

// B=4, S=2048, d=2048, dff=8192. Inputs fp32, output fp32.
// All GEMMs bf16 MFMA (fp32 accum). Weights pre-converted fp32->bf16 per phase.
//
// ws (112 MiB): w0[0,32) x1 -> h2 | w1[32,64) Vt -> f1
//               w2[64,96) Wqkv_bf(24) -> attn(32) | w3[96,112) scP(8,bf16) -> Wo_bf(8) -> W1c(8)+W2c(8)
// d_out (64 MiB fp32): Q bf16 [0,32MiB) + K bf16 [32,64MiB) until PROJ, then src2 fp32 (in-place final).

typedef __attribute__((ext_vector_type(8))) short short8;
typedef __attribute__((ext_vector_type(4))) float floatx4;

#define PLANE 16777216L   // 8192*2048 (Q->K plane stride, elements)
#define SS    4194304L    // 2048*2048 (per-batch matrix, elements)

__device__ __forceinline__ float bf2f(unsigned short u) {
    union { unsigned int i; float f; } v; v.i = ((unsigned int)u) << 16; return v.f;
}
__device__ __forceinline__ unsigned short f2bf(float f) {
    union { float f; unsigned int i; } v; v.f = f;
    unsigned int x = v.i;
    return (unsigned short)((x + 0x7FFFu + ((x >> 16) & 1u)) >> 16);
}
__device__ __forceinline__ uint4 pack8(float4 a, float4 b) {
    unsigned short o[8];
    o[0] = f2bf(a.x); o[1] = f2bf(a.y); o[2] = f2bf(a.z); o[3] = f2bf(a.w);
    o[4] = f2bf(b.x); o[5] = f2bf(b.y); o[6] = f2bf(b.z); o[7] = f2bf(b.w);
    return *(uint4*)o;
}
// async global->LDS, 16B per lane; LDS dest = wave-uniform base + lane*16
__device__ __forceinline__ void gl_lds16(const void* g, void* l) {
    __builtin_amdgcn_global_load_lds(
        (const __attribute__((address_space(1))) void*)g,
        (__attribute__((address_space(3))) void*)l, 16, 0, 0);
}

#define EM_QKV  0
#define EM_SC   1
#define EM_PV   2
#define EM_PROJ 3
#define EM_FFN1 4
#define EM_F2A  5

// C(M,N) = A(M,K) @ B(N,K)^T, both bf16, lda = ldb = K. 128x128 tile, BK=32.
// 256 thr = 4 waves, each wave 64x64 via 4x4 mfma_f32_16x16x32_bf16.
// Staging: global_load_lds width16, unpadded 128x32 LDS, XOR-swizzled 16B chunks
// (slot c holds global chunk c ^ (row&3)) -> 4-way instead of 8-way read conflicts.
template<int EM>
__launch_bounds__(256, 2)
__global__ void gemm_bt(const unsigned short* __restrict__ A,
                        const unsigned short* __restrict__ B,
                        void* __restrict__ Cv, int N, int K,
                        const float* __restrict__ bias,
                        const unsigned short* __restrict__ resid16,
                        unsigned short* __restrict__ outQ,
                        unsigned short* __restrict__ outVt)
{
    constexpr int BM = 128, BN = 128, BK = 32;
    __shared__ __align__(16) unsigned short As[BM * BK];
    __shared__ __align__(16) unsigned short Bs[BN * BK];

    const int m0 = blockIdx.x * BM, n0 = blockIdx.y * BN;
    if (EM == EM_SC && n0 > m0 + (BM - 1)) return;   // fully-masked causal tile

    int kmax = K;
    if (EM == EM_PV) { kmax = m0 + BM; if (kmax > K) kmax = K; }  // P zero past causal edge
    const int nsteps = kmax / BK;

    const int t = threadIdx.x;
    const int lane = t & 63, wave = t >> 6;
    const int q = lane >> 4, ln = lane & 15;
    const int wm = (wave >> 1) * 64, wn = (wave & 1) * 64;

    // staging geometry: wave stages rows [32w,32w+32) of As and Bs, 2 insts of 16 rows each.
    const int r0 = wave * 32;
    const int rA = r0 + (lane >> 2);          // row for inst0; +16 for inst1
    const int cslot = lane & 3;
    const int cg0 = (cslot ^ (rA & 3)) * 8;          // swizzled source chunk
    const int cg1 = (cslot ^ ((rA + 16) & 3)) * 8;
    const unsigned short* Agp0 = A + (long)(m0 + rA) * K + cg0;
    const unsigned short* Agp1 = A + (long)(m0 + rA + 16) * K + cg1;
    const unsigned short* Bgp0 = B + (long)(n0 + rA) * K + cg0;
    const unsigned short* Bgp1 = B + (long)(n0 + rA + 16) * K + cg1;
    unsigned short* lA0 = &As[r0 * 32];
    unsigned short* lA1 = &As[(r0 + 16) * 32];
    unsigned short* lB0 = &Bs[r0 * 32];
    unsigned short* lB1 = &Bs[(r0 + 16) * 32];

    floatx4 acc[4][4];
#pragma unroll
    for (int i = 0; i < 4; ++i)
#pragma unroll
        for (int j = 0; j < 4; ++j) acc[i][j] = (floatx4){0.f, 0.f, 0.f, 0.f};

    for (int s = 0; s < nsteps; ++s) {
        const long off = (long)s * BK;
        __syncthreads();                 // prev ds_reads done before overwrite
        gl_lds16(Agp0 + off, lA0);
        gl_lds16(Agp1 + off, lA1);
        gl_lds16(Bgp0 + off, lB0);
        gl_lds16(Bgp1 + off, lB1);
        __syncthreads();                 // compiler drains vmcnt before barrier -> data visible
        short8 af[4], bfr[4];
#pragma unroll
        for (int i = 0; i < 4; ++i) {
            const int R = wm + 16 * i + ln;
            af[i] = *(const short8*)&As[R * 32 + ((q ^ (R & 3)) * 8)];
        }
#pragma unroll
        for (int j = 0; j < 4; ++j) {
            const int R = wn + 16 * j + ln;
            bfr[j] = *(const short8*)&Bs[R * 32 + ((q ^ (R & 3)) * 8)];
        }
#pragma unroll
        for (int i = 0; i < 4; ++i)
#pragma unroll
            for (int j = 0; j < 4; ++j)
                acc[i][j] = __builtin_amdgcn_mfma_f32_16x16x32_bf16(af[i], bfr[j], acc[i][j], 0, 0, 0);
    }

    // epilogue: within 16x16 tile, row = q*4+reg, col = ln (verified m89/m91)
#pragma unroll
    for (int i = 0; i < 4; ++i) {
#pragma unroll
        for (int r = 0; r < 4; ++r) {
            const int row = m0 + wm + 16 * i + q * 4 + r;
#pragma unroll
            for (int j = 0; j < 4; ++j) {
                const int col = n0 + wn + 16 * j + ln;
                float v = acc[i][j][r];
                const long idx = (long)row * N + col;
                if constexpr (EM == EM_QKV) {
                    v += bias[col];
                    const unsigned short vb = f2bf(v);
                    const int p = col >> 11, c2 = col & 2047;
                    if (p == 0)      outQ[(long)row * 2048 + c2] = vb;
                    else if (p == 1) (outQ + PLANE)[(long)row * 2048 + c2] = vb;
                    else             outVt[(long)(row >> 11) * SS + (long)c2 * 2048 + (row & 2047)] = vb;
                } else if constexpr (EM == EM_SC) {
                    ((unsigned short*)Cv)[idx] = f2bf(v);
                } else if constexpr (EM == EM_PV) {
                    ((unsigned short*)Cv)[idx] = f2bf(v);
                } else if constexpr (EM == EM_PROJ) {
                    v += bias[col] + bf2f(resid16[idx]);    // resid = LN1 out (bf16 x1)
                    ((float*)Cv)[idx] = v;
                } else if constexpr (EM == EM_FFN1) {
                    v = fmaxf(v + bias[col], 0.f);
                    ((unsigned short*)Cv)[idx] = f2bf(v);
                } else { // EM_F2A: accumulate into fp32 src2 (residual already there)
                    ((float*)Cv)[idx] += v;
                }
            }
        }
    }
}

// rows of length 2048: fp32 (stride srcld) -> bf16 (stride 2048)
__launch_bounds__(256)
__global__ void cvt_rows(const float* __restrict__ src, unsigned short* __restrict__ dst, long srcld)
{
    const int row = blockIdx.x, t = threadIdx.x;
    const float* s = src + (long)row * srcld + t * 8;
    float4 a = *(const float4*)s;
    float4 b = *(const float4*)(s + 4);
    *(uint4*)(dst + (long)row * 2048 + t * 8) = pack8(a, b);
}

// LayerNorm: fp32 in (2048 cols), bf16 out; fp32 gamma/beta.
__launch_bounds__(256)
__global__ void layernorm_k(const float* __restrict__ X, unsigned short* __restrict__ Y,
                            const float* __restrict__ g, const float* __restrict__ be)
{
    const int row = blockIdx.x, t = threadIdx.x;
    const float* Xr = X + (long)row * 2048 + t * 8;
    float4 v0 = *(const float4*)Xr;
    float4 v1 = *(const float4*)(Xr + 4);
    float x[8] = {v0.x, v0.y, v0.z, v0.w, v1.x, v1.y, v1.z, v1.w};
    float s = 0.f, ss = 0.f;
#pragma unroll
    for (int k = 0; k < 8; ++k) { s += x[k]; ss += x[k] * x[k]; }
    for (int off = 32; off; off >>= 1) { s += __shfl_down(s, off, 64); ss += __shfl_down(ss, off, 64); }
    __shared__ float red[8];
    const int wave = t >> 6, lane = t & 63;
    if (lane == 0) { red[wave] = s; red[4 + wave] = ss; }
    __syncthreads();
    s  = red[0] + red[1] + red[2] + red[3];
    ss = red[4] + red[5] + red[6] + red[7];
    const float mean = s * (1.f / 2048.f);
    const float var  = ss * (1.f / 2048.f) - mean * mean;
    const float rstd = rsqrtf(var + 1e-5f);
    unsigned short o[8];
#pragma unroll
    for (int k = 0; k < 8; ++k) {
        const int col = t * 8 + k;
        o[k] = f2bf((x[k] - mean) * rstd * g[col] + be[col]);
    }
    *(uint4*)(Y + (long)row * 2048 + t * 8) = *(uint4*)o;
}

// In-place RoPE on bf16 Q (blockIdx.y=0) / K (=1), replicating the reference quirk:
// emb = concat(sin(sp),cos(sp)); c=cos(emb), s=sin(emb); rh = concat(-x[::2], x[1::2]).
__launch_bounds__(256)
__global__ void rope_inplace(unsigned short* __restrict__ Q, unsigned short* __restrict__ K)
{
    __shared__ __align__(16) unsigned short rowbuf[2048];
    const int row = blockIdx.x;              // 0..8191 (b*2048+p)
    const int mtx = blockIdx.y;
    unsigned short* X = (mtx ? K : Q) + (long)row * 2048;
    const int t = threadIdx.x;
    *(uint4*)&rowbuf[t * 8] = *(const uint4*)(X + t * 8);
    __syncthreads();
    const int p = row & 2047;
    const float sgn = mtx ? -1.f : 1.f;
    unsigned short o[8];
#pragma unroll
    for (int e = 0; e < 8; ++e) {
        const int j = t * 8 + e;
        const int i = j & 1023;
        const float freq = __expf(-(float)i * (9.210340371976184f / 1024.0f)); // 10000^(-i/1024)
        const float sp = (float)p * freq;
        const float emb = (j < 1024) ? sinf(sp) : cosf(sp);
        float se, ce;
        sincosf(emb, &se, &ce);
        const int pj = (j < 1024) ? (2 * j) : (2 * j - 2047);
        float xp = bf2f(rowbuf[pj]);
        if (j < 1024) xp = -xp;
        o[e] = f2bf(bf2f(rowbuf[j]) * ce + sgn * xp * se);
    }
    *(uint4*)(X + t * 8) = *(uint4*)o;
}

// Causal softmax in-place on bf16 scores (2048x2048); full rows written (zeros past edge).
__launch_bounds__(256)
__global__ void softmax_causal(unsigned short* __restrict__ S)
{
    const int qq = blockIdx.x;
    const int L = qq + 1;
    unsigned short* srow = S + (long)qq * 2048;
    const int t = threadIdx.x;
    const float scale = 0.022097086912079608f; // 1/sqrt(2048)
    float vals[8];
    float m = -1e30f;
#pragma unroll
    for (int u = 0; u < 8; ++u) {
        const int i2 = t + 256 * u;
        vals[u] = (i2 < L) ? bf2f(srow[i2]) * scale : -1e30f;
        m = fmaxf(m, vals[u]);
    }
    for (int off = 32; off; off >>= 1) m = fmaxf(m, __shfl_down(m, off, 64));
    __shared__ float red[8];
    const int wave = t >> 6, lane = t & 63;
    if (lane == 0) red[wave] = m;
    __syncthreads();
    m = fmaxf(fmaxf(red[0], red[1]), fmaxf(red[2], red[3]));
    float sum = 0.f;
#pragma unroll
    for (int u = 0; u < 8; ++u) {
        float e = __expf(vals[u] - m);
        e = (t + 256 * u < L) ? e : 0.f;
        vals[u] = e; sum += e;
    }
    for (int off = 32; off; off >>= 1) sum += __shfl_down(sum, off, 64);
    if (lane == 0) red[4 + wave] = sum;
    __syncthreads();
    sum = red[4] + red[5] + red[6] + red[7];
    const float inv = 1.0f / sum;
#pragma unroll
    for (int u = 0; u < 8; ++u) srow[t + 256 * u] = f2bf(vals[u] * inv);
}

// io += b2 (in place on d_out; src2 already holds residual + FFN2 accumulation)
__launch_bounds__(256)
__global__ void final_add(float* __restrict__ io, const float* __restrict__ b2)
{
    const int row = blockIdx.x, t = threadIdx.x;
    const long base = (long)row * 2048 + t * 8;
    float4 a0 = *(const float4*)(io + base);
    float4 a1 = *(const float4*)(io + base + 4);
    float4 c0 = *(const float4*)(b2 + t * 8);
    float4 c1 = *(const float4*)(b2 + t * 8 + 4);
    a0.x += c0.x; a0.y += c0.y; a0.z += c0.z; a0.w += c0.w;
    a1.x += c1.x; a1.y += c1.y; a1.z += c1.z; a1.w += c1.w;
    *(float4*)(io + base) = a0;
    *(float4*)(io + base + 4) = a1;
}

extern "C" void kernel_launch(void* const* d_in, const int* in_sizes, int n_in,
                              void* d_out, int out_size, void* d_ws, size_t ws_size,
                              hipStream_t stream)
{
    const float* src  = (const float*)d_in[0];
    const float* Wqkv = (const float*)d_in[1];
    const float* bqkv = (const float*)d_in[2];
    const float* Wo   = (const float*)d_in[3];
    const float* bo   = (const float*)d_in[4];
    const float* W1   = (const float*)d_in[5];
    const float* b1   = (const float*)d_in[6];
    const float* W2   = (const float*)d_in[7];
    const float* b2   = (const float*)d_in[8];
    const float* g1   = (const float*)d_in[9];
    const float* be1  = (const float*)d_in[10];
    const float* g2   = (const float*)d_in[11];
    const float* be2  = (const float*)d_in[12];

    char* ws = (char*)d_ws;
    const long MB = 1LL << 20;
    unsigned short* x1    = (unsigned short*)ws;                 // w0: LN1 out -> h2
    unsigned short* Vt    = (unsigned short*)(ws + 32 * MB);     // w1: Vt -> f1
    unsigned short* Wqbf  = (unsigned short*)(ws + 64 * MB);     // w2: Wqkv_bf -> attn
    unsigned short* attn  = (unsigned short*)(ws + 64 * MB);
    unsigned short* scP   = (unsigned short*)(ws + 96 * MB);     // w3: bf16 scores/P (8 MiB)
    unsigned short* Wobf  = (unsigned short*)(ws + 96 * MB);     //     -> Wo_bf (8 MiB)
    unsigned short* W1c   = (unsigned short*)(ws + 96 * MB);     //     -> W1 chunk (8 MiB)
    unsigned short* W2c   = (unsigned short*)(ws + 104 * MB);    //     -> W2 chunk (8 MiB)
    unsigned short* h2    = x1;
    unsigned short* f1    = Vt;

    unsigned short* Q    = (unsigned short*)d_out;               // Q [0,32MiB), K [32,64MiB)
    float*          src2 = (float*)d_out;                        // after PROJ (Q,K dead)
    float*          out  = (float*)d_out;

    const dim3 blk(256);

    cvt_rows<<<6144, blk, 0, stream>>>(Wqkv, Wqbf, 2048);
    layernorm_k<<<8192, blk, 0, stream>>>(src, x1, g1, be1);
    gemm_bt<EM_QKV><<<dim3(64, 48), blk, 0, stream>>>(
        x1, Wqbf, nullptr, 6144, 2048, bqkv, nullptr, Q, Vt);
    rope_inplace<<<dim3(8192, 2), blk, 0, stream>>>(Q, Q + PLANE);

    for (int b = 0; b < 4; ++b) {
        gemm_bt<EM_SC><<<dim3(16, 16), blk, 0, stream>>>(
            Q + b * SS, Q + PLANE + b * SS, scP, 2048, 2048, nullptr, nullptr, nullptr, nullptr);
        softmax_causal<<<2048, blk, 0, stream>>>(scP);
        gemm_bt<EM_PV><<<dim3(16, 16), blk, 0, stream>>>(
            scP, Vt + b * SS, attn + b * SS, 2048, 2048, nullptr, nullptr, nullptr, nullptr);
    }

    cvt_rows<<<2048, blk, 0, stream>>>(Wo, Wobf, 2048);
    gemm_bt<EM_PROJ><<<dim3(64, 16), blk, 0, stream>>>(
        attn, Wobf, src2, 2048, 2048, bo, x1, nullptr, nullptr);
    layernorm_k<<<8192, blk, 0, stream>>>(src2, h2, g2, be2);

    for (int c = 0; c < 4; ++c) {
        cvt_rows<<<2048, blk, 0, stream>>>(W1 + (long)c * 2048 * 2048, W1c, 2048);
        cvt_rows<<<2048, blk, 0, stream>>>(W2 + (long)c * 2048, W2c, 8192);
        gemm_bt<EM_FFN1><<<dim3(64, 16), blk, 0, stream>>>(
            h2, W1c, f1, 2048, 2048, b1 + c * 2048, nullptr, nullptr, nullptr);
        gemm_bt<EM_F2A><<<dim3(64, 16), blk, 0, stream>>>(
            f1, W2c, src2, 2048, 2048, nullptr, nullptr, nullptr, nullptr);
    }
    final_add<<<8192, blk, 0, stream>>>(out, b2);
}